// Round 2
// baseline (349.969 us; speedup 1.0000x reference)
//
#include <hip/hip_runtime.h>
#include <hip/hip_cooperative_groups.h>
#include <math.h>

namespace cg = cooperative_groups;

#define HW     16384
#define CDIM   10
#define NPIX   131072        // B*H*W
#define NPLANE 1310720       // B*C*H*W
#define BN_N   131072.0f
#define EPS_BN 1e-5f

__device__ __forceinline__ float sigf(float x) { return 1.0f / (1.0f + __expf(-x)); }
__device__ __forceinline__ float tanh_fast(float x) {
    x = fminf(fmaxf(x, -15.0f), 15.0f);
    float e = __expf(2.0f * x);
    return (e - 1.0f) / (e + 1.0f);
}
__device__ __forceinline__ float wred(float v) {
#pragma unroll
    for (int o = 32; o; o >>= 1) v += __shfl_down(v, o, 64);
    return v;
}
__device__ __forceinline__ float agent_load(const float* a) {
    return __hip_atomic_load(a, __ATOMIC_RELAXED, __HIP_MEMORY_SCOPE_AGENT);
}

struct P {
    const float *f0, *f1, *h0, *h1, *h2;
    const float *W_att, *b_att;
    const float *W_r1, *g_r1, *be_r1, *W_r2, *g_r2, *be_r2;
    const float *Wg0, *bg0, *Wc0, *Wg1, *bg1, *Wc1;
    float *node0, *node1, *attO;
    float *stats;   // [0..19]=sum1, [20..39]=sq1, [40..49]=sum2, [50..59]=sq2
};

__global__ __launch_bounds__(256, 2) void fused(P p)
{
    cg::grid_group grid = cg::this_grid();
    __shared__ float sW1[400], sW2[200], sWc0[200], sWc1[200];
    __shared__ float sWatt[20], sWg0[40], sWg1[40];
    __shared__ float sAB[80];      // a1[0:20], b1[20:40], a2[40:50], b2[50:60]
    __shared__ float sPart[160];   // wave partials
    const int tid  = threadIdx.x;
    const int wave = tid >> 6, lane = tid & 63;

    for (int i = tid; i < 400; i += 256) sW1[i] = p.W_r1[i];
    for (int i = tid; i < 200; i += 256) {
        sW2[i]  = p.W_r2[i];
        sWc0[i] = p.Wc0[i];
        sWc1[i] = p.Wc1[i];
    }
    if (tid < 20) sWatt[tid] = p.W_att[tid];
    if (tid < 40) { sWg0[tid] = p.Wg0[tid]; sWg1[tid] = p.Wg1[tid]; }
    __syncthreads();

    const int px   = blockIdx.x * 256 + tid;
    const int b    = px >> 14, s = px & 16383;
    const int base = b * (CDIM * HW) + s;

    // ---------------- Phase 1 ----------------
    float x[20];   // [f1, (h1+h2)*att] — lives across both grid syncs
    {
        float vh1[10], vh2[10];
#pragma unroll
        for (int c = 0; c < 10; c++) {
            vh1[c]  = p.h1[base + c * HW];
            vh2[c]  = p.h2[base + c * HW];
            x[c]    = p.f1[base + c * HW];
        }
        float z = p.b_att[0];
#pragma unroll
        for (int c = 0; c < 10; c++) z += sWatt[c] * vh1[c] + sWatt[10 + c] * vh2[c];
        const float att = sigf(z);
        p.attO[px] = att;
#pragma unroll
        for (int c = 0; c < 10; c++) x[10 + c] = (vh1[c] + vh2[c]) * att;

        // BN1 stats of y1 = W_r1 @ x
#pragma unroll
        for (int o = 0; o < 20; o++) {
            float acc = 0.0f;
#pragma unroll
            for (int i = 0; i < 20; i++) acc = fmaf(sW1[o * 20 + i], x[i], acc);
            float rs = wred(acc);
            float rq = wred(acc * acc);
            if (lane == 0) { sPart[wave * 40 + o] = rs; sPart[wave * 40 + 20 + o] = rq; }
        }

        // node0 = GRU0(x=h0, h=f0)
        float vf0[10], vh0[10];
#pragma unroll
        for (int c = 0; c < 10; c++) { vf0[c] = p.f0[base + c * HW]; vh0[c] = p.h0[base + c * HW]; }
        float g0 = p.bg0[0], g1 = p.bg0[1];
#pragma unroll
        for (int i = 0; i < 10; i++) {
            g0 += sWg0[i] * vh0[i] + sWg0[10 + i] * vf0[i];
            g1 += sWg0[20 + i] * vh0[i] + sWg0[30 + i] * vf0[i];
        }
        const float r = sigf(g0), u = sigf(g1);
#pragma unroll
        for (int o = 0; o < 10; o++) {
            float acc = 0.0f;
#pragma unroll
            for (int i = 0; i < 10; i++) acc = fmaf(sWc0[o * 20 + i], vh0[i], acc);
#pragma unroll
            for (int i = 0; i < 10; i++) acc = fmaf(sWc0[o * 20 + 10 + i], r * vf0[i], acc);
            p.node0[base + o * HW] = (1.0f - u) * vf0[o] + u * tanh_fast(acc);
        }
    }
    __syncthreads();
    if (tid < 40) {
        float t = sPart[tid] + sPart[40 + tid] + sPart[80 + tid] + sPart[120 + tid];
        atomicAdd(&p.stats[tid], t);
    }
    __threadfence();
    grid.sync();

    // ---------------- Phase 2 ----------------
    if (tid < 20) {
        float sm = agent_load(&p.stats[tid]);
        float sq = agent_load(&p.stats[20 + tid]);
        float mean = sm * (1.0f / BN_N);
        float var  = sq * (1.0f / BN_N) - mean * mean;
        float a = p.g_r1[tid] * rsqrtf(var + EPS_BN);
        sAB[tid]      = a;
        sAB[20 + tid] = p.be_r1[tid] - mean * a;
    }
    __syncthreads();

    float y2[10];
    {
        float x2[20];
#pragma unroll
        for (int o = 0; o < 20; o++) {
            float acc = 0.0f;
#pragma unroll
            for (int i = 0; i < 20; i++) acc = fmaf(sW1[o * 20 + i], x[i], acc);
            x2[o] = fmaxf(fmaf(sAB[o], acc, sAB[20 + o]), 0.0f);
        }
#pragma unroll
        for (int o = 0; o < 10; o++) {
            float acc = 0.0f;
#pragma unroll
            for (int i = 0; i < 20; i++) acc = fmaf(sW2[o * 20 + i], x2[i], acc);
            y2[o] = acc;
            float rs = wred(acc);
            float rq = wred(acc * acc);
            if (lane == 0) { sPart[wave * 20 + o] = rs; sPart[wave * 20 + 10 + o] = rq; }
        }
    }
    __syncthreads();
    if (tid < 20) {
        float t = sPart[tid] + sPart[20 + tid] + sPart[40 + tid] + sPart[60 + tid];
        atomicAdd(&p.stats[40 + tid], t);
    }
    __threadfence();
    grid.sync();

    // ---------------- Phase 3 ----------------
    if (tid < 10) {
        float sm = agent_load(&p.stats[40 + tid]);
        float sq = agent_load(&p.stats[50 + tid]);
        float mean = sm * (1.0f / BN_N);
        float var  = sq * (1.0f / BN_N) - mean * mean;
        float a = p.g_r2[tid] * rsqrtf(var + EPS_BN);
        sAB[40 + tid] = a;
        sAB[50 + tid] = p.be_r2[tid] - mean * a;
    }
    __syncthreads();

    {
        float comp[10];
#pragma unroll
        for (int c = 0; c < 10; c++)
            comp[c] = fmaxf(fmaf(sAB[40 + c], y2[c], sAB[50 + c]), 0.0f);
        // node1 = GRU1(x=comp, h=f1); f1 still lives in x[0..9]
        float g0 = p.bg1[0], g1 = p.bg1[1];
#pragma unroll
        for (int i = 0; i < 10; i++) {
            g0 += sWg1[i] * comp[i] + sWg1[10 + i] * x[i];
            g1 += sWg1[20 + i] * comp[i] + sWg1[30 + i] * x[i];
        }
        const float r = sigf(g0), u = sigf(g1);
#pragma unroll
        for (int o = 0; o < 10; o++) {
            float acc = 0.0f;
#pragma unroll
            for (int i = 0; i < 10; i++) acc = fmaf(sWc1[o * 20 + i], comp[i], acc);
#pragma unroll
            for (int i = 0; i < 10; i++) acc = fmaf(sWc1[o * 20 + 10 + i], r * x[i], acc);
            p.node1[base + o * HW] = (1.0f - u) * x[o] + u * tanh_fast(acc);
        }
    }
}

extern "C" void kernel_launch(void* const* d_in, const int* in_sizes, int n_in,
                              void* d_out, int out_size, void* d_ws, size_t ws_size,
                              hipStream_t stream) {
    P p;
    p.f0    = (const float*)d_in[0];
    p.f1    = (const float*)d_in[1];
    p.h0    = (const float*)d_in[2];
    p.h1    = (const float*)d_in[3];
    p.h2    = (const float*)d_in[4];
    p.W_att = (const float*)d_in[5];
    p.b_att = (const float*)d_in[6];
    p.W_r1  = (const float*)d_in[7];
    p.g_r1  = (const float*)d_in[8];
    p.be_r1 = (const float*)d_in[9];
    p.W_r2  = (const float*)d_in[10];
    p.g_r2  = (const float*)d_in[11];
    p.be_r2 = (const float*)d_in[12];
    p.Wg0   = (const float*)d_in[13];
    p.bg0   = (const float*)d_in[14];
    p.Wc0   = (const float*)d_in[15];
    p.Wg1   = (const float*)d_in[16];
    p.bg1   = (const float*)d_in[17];
    p.Wc1   = (const float*)d_in[18];

    float* out = (float*)d_out;
    p.node0 = out;
    p.node1 = out + NPLANE;
    p.attO  = out + 2 * NPLANE;
    p.stats = (float*)d_ws;   // 60 floats

    hipMemsetAsync(p.stats, 0, 64 * sizeof(float), stream);

    void* args[] = { &p };
    hipLaunchCooperativeKernel((void*)fused, dim3(NPIX / 256), dim3(256),
                               args, 0, stream);
}

// Round 3
// 168.386 us; speedup vs baseline: 2.0784x; 2.0784x over previous
//
#include <hip/hip_runtime.h>
#include <math.h>

#define HW     16384
#define CDIM   10
#define NPIX   131072        // B*H*W
#define NPLANE 1310720       // B*C*H*W
#define NBLK   512           // grid blocks, 256 thr each, 1 px/thread
#define BN_N   131072.0f
#define EPS_BN 1e-5f

__device__ __forceinline__ float sigf(float x) { return 1.0f / (1.0f + __expf(-x)); }
__device__ __forceinline__ float tanh_fast(float x) {
    x = fminf(fmaxf(x, -15.0f), 15.0f);
    float e = __expf(2.0f * x);
    return (e - 1.0f) / (e + 1.0f);
}
__device__ __forceinline__ float wred(float v) {
#pragma unroll
    for (int o = 32; o; o >>= 1) v += __shfl_down(v, o, 64);
    return v;
}

// ---------------- K1: node0 (GRU0), comp_att, BN1-stat partials ----------------
__global__ __launch_bounds__(256) void kernA(
    const float* __restrict__ f0, const float* __restrict__ f1,
    const float* __restrict__ h0, const float* __restrict__ h1, const float* __restrict__ h2,
    const float* __restrict__ W_att, const float* __restrict__ b_att,
    const float* __restrict__ W_r1,
    const float* __restrict__ Wg0, const float* __restrict__ bg0, const float* __restrict__ Wc0,
    float* __restrict__ node0, float* __restrict__ att_out, float* __restrict__ part1)
{
    __shared__ float sW1[400], sWatt[20], sWg[40], sWc[200];
    __shared__ float sPart[4 * 40];
    const int tid = threadIdx.x;
    const int wave = tid >> 6, lane = tid & 63;
    const int px = blockIdx.x * 256 + tid;
    const int b = px >> 14, s = px & 16383;
    const int base = b * (CDIM * HW) + s;

    // issue ALL per-thread global loads first (max MLP)
    float vh1[10], vh2[10], vf1[10], vf0[10], vh0[10];
#pragma unroll
    for (int c = 0; c < 10; c++) {
        vh1[c] = h1[base + c * HW];
        vh2[c] = h2[base + c * HW];
        vf1[c] = f1[base + c * HW];
        vf0[c] = f0[base + c * HW];
        vh0[c] = h0[base + c * HW];
    }
    // weight staging overlaps with the loads above
    for (int i = tid; i < 400; i += 256) sW1[i] = W_r1[i];
    for (int i = tid; i < 200; i += 256) sWc[i] = Wc0[i];
    if (tid < 20) sWatt[tid] = W_att[tid];
    if (tid < 40) sWg[tid] = Wg0[tid];
    __syncthreads();

    // comp_att
    float z = b_att[0];
#pragma unroll
    for (int c = 0; c < 10; c++) z += sWatt[c] * vh1[c] + sWatt[10 + c] * vh2[c];
    const float att = sigf(z);
    att_out[px] = att;

    float x[20];
#pragma unroll
    for (int c = 0; c < 10; c++) { x[c] = vf1[c]; x[10 + c] = (vh1[c] + vh2[c]) * att; }
#pragma unroll
    for (int o = 0; o < 20; o++) {
        float acc = 0.0f;
#pragma unroll
        for (int i = 0; i < 20; i++) acc = fmaf(sW1[o * 20 + i], x[i], acc);
        float rs = wred(acc);
        float rq = wred(acc * acc);
        if (lane == 0) { sPart[wave * 40 + o] = rs; sPart[wave * 40 + 20 + o] = rq; }
    }

    // node0 = GRU0(x=h0, h=f0)
    float g0 = bg0[0], g1 = bg0[1];
#pragma unroll
    for (int i = 0; i < 10; i++) {
        g0 += sWg[i] * vh0[i] + sWg[10 + i] * vf0[i];
        g1 += sWg[20 + i] * vh0[i] + sWg[30 + i] * vf0[i];
    }
    const float r = sigf(g0), u = sigf(g1);
#pragma unroll
    for (int o = 0; o < 10; o++) {
        float acc = 0.0f;
#pragma unroll
        for (int i = 0; i < 10; i++) acc = fmaf(sWc[o * 20 + i], vh0[i], acc);
#pragma unroll
        for (int i = 0; i < 10; i++) acc = fmaf(sWc[o * 20 + 10 + i], r * vf0[i], acc);
        __builtin_nontemporal_store((1.0f - u) * vf0[o] + u * tanh_fast(acc),
                                    &node0[base + o * HW]);
    }

    __syncthreads();
    if (tid < 64) {
        float t = 0.0f;
        if (tid < 40)
            t = sPart[tid] + sPart[40 + tid] + sPart[80 + tid] + sPart[120 + tid];
        part1[blockIdx.x * 64 + tid] = t;   // plain store, no atomics, no init needed
    }
}

// ---------------- K2: reduce BN1, recompute y1, BN1+ReLU, y2, BN2-stat partials ----------------
__global__ __launch_bounds__(256) void kernC(
    const float* __restrict__ f1, const float* __restrict__ h1, const float* __restrict__ h2,
    const float* __restrict__ att_in,
    const float* __restrict__ W_r1, const float* __restrict__ g_r1, const float* __restrict__ be_r1,
    const float* __restrict__ W_r2,
    const float* __restrict__ part1, float* __restrict__ y2out, float* __restrict__ part2)
{
    __shared__ float sW1[400], sW2[200], sAB[40];
    __shared__ float sRed[256];
    __shared__ float sPart[4 * 20];
    const int tid = threadIdx.x;
    const int wave = tid >> 6, lane = tid & 63;
    const int px = blockIdx.x * 256 + tid;
    const int b = px >> 14, s = px & 16383;
    const int base = b * (CDIM * HW) + s;

    // per-thread tensor loads first
    float vh1[10], vh2[10], vf1[10];
#pragma unroll
    for (int c = 0; c < 10; c++) {
        vh1[c] = h1[base + c * HW];
        vh2[c] = h2[base + c * HW];
        vf1[c] = f1[base + c * HW];
    }
    const float att = att_in[px];

    for (int i = tid; i < 400; i += 256) sW1[i] = W_r1[i];
    for (int i = tid; i < 200; i += 256) sW2[i] = W_r2[i];

    // reduce part1 [512][64] -> stats (L2-hot, coalesced)
    {
        const int j = tid & 63, q = tid >> 6;
        float acc = 0.0f;
#pragma unroll 8
        for (int bb = q; bb < NBLK; bb += 4) acc += part1[bb * 64 + j];
        sRed[tid] = acc;
    }
    __syncthreads();
    if (tid < 20) {
        float sm = sRed[tid]       + sRed[64 + tid]      + sRed[128 + tid]      + sRed[192 + tid];
        float sq = sRed[20 + tid]  + sRed[84 + tid]      + sRed[148 + tid]      + sRed[212 + tid];
        float mean = sm * (1.0f / BN_N);
        float var  = sq * (1.0f / BN_N) - mean * mean;
        float a = g_r1[tid] * rsqrtf(var + EPS_BN);
        sAB[tid]      = a;
        sAB[20 + tid] = be_r1[tid] - mean * a;
    }
    __syncthreads();

    float x[20];
#pragma unroll
    for (int c = 0; c < 10; c++) { x[c] = vf1[c]; x[10 + c] = (vh1[c] + vh2[c]) * att; }
    float x2[20];
#pragma unroll
    for (int o = 0; o < 20; o++) {
        float acc = 0.0f;
#pragma unroll
        for (int i = 0; i < 20; i++) acc = fmaf(sW1[o * 20 + i], x[i], acc);
        x2[o] = fmaxf(fmaf(sAB[o], acc, sAB[20 + o]), 0.0f);
    }
    const int base2 = b * (10 * HW) + s;
#pragma unroll
    for (int o = 0; o < 10; o++) {
        float acc = 0.0f;
#pragma unroll
        for (int i = 0; i < 20; i++) acc = fmaf(sW2[o * 20 + i], x2[i], acc);
        y2out[base2 + o * HW] = acc;
        float rs = wred(acc);
        float rq = wred(acc * acc);
        if (lane == 0) { sPart[wave * 20 + o] = rs; sPart[wave * 20 + 10 + o] = rq; }
    }
    __syncthreads();
    if (tid < 64) {
        float t = 0.0f;
        if (tid < 20)
            t = sPart[tid] + sPart[20 + tid] + sPart[40 + tid] + sPart[60 + tid];
        part2[blockIdx.x * 64 + tid] = t;
    }
}

// ---------------- K3: reduce BN2, comp_full, node1 (GRU1) ----------------
__global__ __launch_bounds__(256) void kernE(
    const float* __restrict__ f1, const float* __restrict__ y2in,
    const float* __restrict__ part2,
    const float* __restrict__ g_r2, const float* __restrict__ be_r2,
    const float* __restrict__ Wg1, const float* __restrict__ bg1, const float* __restrict__ Wc1,
    float* __restrict__ node1)
{
    __shared__ float sWg[40], sWc[200], sAB[20];
    __shared__ float sRed[256];
    const int tid = threadIdx.x;
    const int px = blockIdx.x * 256 + tid;
    const int b = px >> 14, s = px & 16383;
    const int base = b * (CDIM * HW) + s;

    float vf1[10], vy2[10];
#pragma unroll
    for (int c = 0; c < 10; c++) {
        vf1[c] = f1[base + c * HW];
        vy2[c] = y2in[base + c * HW];
    }
    for (int i = tid; i < 200; i += 256) sWc[i] = Wc1[i];
    if (tid < 40) sWg[tid] = Wg1[tid];

    {
        const int j = tid & 63, q = tid >> 6;
        float acc = 0.0f;
#pragma unroll 8
        for (int bb = q; bb < NBLK; bb += 4) acc += part2[bb * 64 + j];
        sRed[tid] = acc;
    }
    __syncthreads();
    if (tid < 10) {
        float sm = sRed[tid]      + sRed[64 + tid]      + sRed[128 + tid]      + sRed[192 + tid];
        float sq = sRed[10 + tid] + sRed[74 + tid]      + sRed[138 + tid]      + sRed[202 + tid];
        float mean = sm * (1.0f / BN_N);
        float var  = sq * (1.0f / BN_N) - mean * mean;
        float a = g_r2[tid] * rsqrtf(var + EPS_BN);
        sAB[tid]      = a;
        sAB[10 + tid] = be_r2[tid] - mean * a;
    }
    __syncthreads();

    float comp[10];
#pragma unroll
    for (int c = 0; c < 10; c++)
        comp[c] = fmaxf(fmaf(sAB[c], vy2[c], sAB[10 + c]), 0.0f);
    float g0 = bg1[0], g1 = bg1[1];
#pragma unroll
    for (int i = 0; i < 10; i++) {
        g0 += sWg[i] * comp[i] + sWg[10 + i] * vf1[i];
        g1 += sWg[20 + i] * comp[i] + sWg[30 + i] * vf1[i];
    }
    const float r = sigf(g0), u = sigf(g1);
#pragma unroll
    for (int o = 0; o < 10; o++) {
        float acc = 0.0f;
#pragma unroll
        for (int i = 0; i < 10; i++) acc = fmaf(sWc[o * 20 + i], comp[i], acc);
#pragma unroll
        for (int i = 0; i < 10; i++) acc = fmaf(sWc[o * 20 + 10 + i], r * vf1[i], acc);
        __builtin_nontemporal_store((1.0f - u) * vf1[o] + u * tanh_fast(acc),
                                    &node1[base + o * HW]);
    }
}

extern "C" void kernel_launch(void* const* d_in, const int* in_sizes, int n_in,
                              void* d_out, int out_size, void* d_ws, size_t ws_size,
                              hipStream_t stream) {
    const float* f0    = (const float*)d_in[0];
    const float* f1    = (const float*)d_in[1];
    const float* h0    = (const float*)d_in[2];
    const float* h1    = (const float*)d_in[3];
    const float* h2    = (const float*)d_in[4];
    const float* W_att = (const float*)d_in[5];
    const float* b_att = (const float*)d_in[6];
    const float* W_r1  = (const float*)d_in[7];
    const float* g_r1  = (const float*)d_in[8];
    const float* be_r1 = (const float*)d_in[9];
    const float* W_r2  = (const float*)d_in[10];
    const float* g_r2  = (const float*)d_in[11];
    const float* be_r2 = (const float*)d_in[12];
    const float* Wg0   = (const float*)d_in[13];
    const float* bg0   = (const float*)d_in[14];
    const float* Wc0   = (const float*)d_in[15];
    const float* Wg1   = (const float*)d_in[16];
    const float* bg1   = (const float*)d_in[17];
    const float* Wc1   = (const float*)d_in[18];

    float* out   = (float*)d_out;
    float* node0 = out;
    float* node1 = out + NPLANE;
    float* attO  = out + 2 * NPLANE;

    float* y2    = (float*)d_ws;                    // 10*NPIX floats
    float* part1 = y2 + (size_t)10 * NPIX;          // 512*64 floats
    float* part2 = part1 + (size_t)NBLK * 64;       // 512*64 floats

    dim3 grid(NBLK), blk(256);
    kernA<<<grid, blk, 0, stream>>>(f0, f1, h0, h1, h2, W_att, b_att, W_r1,
                                    Wg0, bg0, Wc0, node0, attO, part1);
    kernC<<<grid, blk, 0, stream>>>(f1, h1, h2, attO, W_r1, g_r1, be_r1, W_r2,
                                    part1, y2, part2);
    kernE<<<grid, blk, 0, stream>>>(f1, y2, part2, g_r2, be_r2, Wg1, bg1, Wc1,
                                    node1);
}

// Round 4
// 158.505 us; speedup vs baseline: 2.2079x; 1.0623x over previous
//
#include <hip/hip_runtime.h>
#include <math.h>

#define HW     16384
#define NPIX   131072        // B*H*W
#define NPLANE 1310720       // B*C*H*W
#define NG     65536         // pixel pairs (2 px/thread)
#define TPB    128
#define NBLK   (NG / TPB)    // 512 blocks, 2 waves each -> 4 waves/CU
#define BN_N   131072.0f
#define EPS_BN 1e-5f

typedef float v2f __attribute__((ext_vector_type(2)));

__device__ __forceinline__ float sigf(float x) { return 1.0f / (1.0f + __expf(-x)); }
__device__ __forceinline__ float tanh_fast(float x) {
    x = fminf(fmaxf(x, -15.0f), 15.0f);
    float e = __expf(2.0f * x);
    return (e - 1.0f) / (e + 1.0f);
}
__device__ __forceinline__ float wred(float v) {
#pragma unroll
    for (int o = 32; o; o >>= 1) v += __shfl_down(v, o, 64);
    return v;
}
__device__ __forceinline__ float2 ld2(const float* p) {
    return *(const float2*)p;
}
__device__ __forceinline__ void nt_store2(float2 v, float* p) {
    v2f t; t.x = v.x; t.y = v.y;
    __builtin_nontemporal_store(t, (v2f*)p);
}

// ---------------- K1: node0 (GRU0), comp_att, BN1 stats (atomic) ----------------
__global__ __launch_bounds__(TPB, 1) void kernA(
    const float* __restrict__ f0, const float* __restrict__ f1,
    const float* __restrict__ h0, const float* __restrict__ h1, const float* __restrict__ h2,
    const float* __restrict__ W_att, const float* __restrict__ b_att,
    const float* __restrict__ W_r1,
    const float* __restrict__ Wg0, const float* __restrict__ bg0, const float* __restrict__ Wc0,
    float* __restrict__ node0, float* __restrict__ att_out, float* __restrict__ stats)
{
    __shared__ float sPart[2 * 40];
    const int tid = threadIdx.x, wave = tid >> 6, lane = tid & 63;
    const int g = blockIdx.x * TPB + tid;
    const int b = g >> 13, sp = (g & 8191) << 1;
    const int base = b * (10 * HW) + sp;

    // hoist ALL global loads (float2 -> dwordx2, ~25 KB in flight per wave)
    float2 vf0[10], vf1[10], vh0[10], vh1[10], vh2[10];
#pragma unroll
    for (int c = 0; c < 10; c++) {
        vh1[c] = ld2(h1 + base + c * HW);
        vh2[c] = ld2(h2 + base + c * HW);
        vf1[c] = ld2(f1 + base + c * HW);
        vf0[c] = ld2(f0 + base + c * HW);
        vh0[c] = ld2(h0 + base + c * HW);
    }

    // comp_att (weights are wave-uniform -> scalar loads)
    float zx = b_att[0], zy = zx;
#pragma unroll
    for (int c = 0; c < 10; c++) {
        zx += W_att[c] * vh1[c].x + W_att[10 + c] * vh2[c].x;
        zy += W_att[c] * vh1[c].y + W_att[10 + c] * vh2[c].y;
    }
    const float ax_ = sigf(zx), ay_ = sigf(zy);
    nt_store2(make_float2(ax_, ay_), att_out + 2 * g);

    // x = [f1, (h1+h2)*att]; BN1 stats of y1 = W_r1 @ x
    float2 x[20];
#pragma unroll
    for (int c = 0; c < 10; c++) {
        x[c] = vf1[c];
        x[10 + c] = make_float2((vh1[c].x + vh2[c].x) * ax_,
                                (vh1[c].y + vh2[c].y) * ay_);
    }
#pragma unroll
    for (int o = 0; o < 20; o++) {
        float sx = 0.0f, sy = 0.0f;
#pragma unroll
        for (int i = 0; i < 20; i++) {
            const float w = W_r1[o * 20 + i];
            sx = fmaf(w, x[i].x, sx);
            sy = fmaf(w, x[i].y, sy);
        }
        float rs = wred(sx + sy);
        float rq = wred(sx * sx + sy * sy);
        if (lane == 0) { sPart[wave * 40 + o] = rs; sPart[wave * 40 + 20 + o] = rq; }
    }

    // node0 = GRU0(x=h0, h=f0)
    float g0x = bg0[0], g1x = bg0[1], g0y = bg0[0], g1y = bg0[1];
#pragma unroll
    for (int i = 0; i < 10; i++) {
        g0x += Wg0[i] * vh0[i].x + Wg0[10 + i] * vf0[i].x;
        g0y += Wg0[i] * vh0[i].y + Wg0[10 + i] * vf0[i].y;
        g1x += Wg0[20 + i] * vh0[i].x + Wg0[30 + i] * vf0[i].x;
        g1y += Wg0[20 + i] * vh0[i].y + Wg0[30 + i] * vf0[i].y;
    }
    const float rx = sigf(g0x), ux = sigf(g1x);
    const float ry = sigf(g0y), uy = sigf(g1y);
#pragma unroll
    for (int o = 0; o < 10; o++) {
        float cx = 0.0f, cy = 0.0f;
#pragma unroll
        for (int i = 0; i < 10; i++) {
            const float w0 = Wc0[o * 20 + i], w1 = Wc0[o * 20 + 10 + i];
            cx = fmaf(w0, vh0[i].x, cx); cx = fmaf(w1, rx * vf0[i].x, cx);
            cy = fmaf(w0, vh0[i].y, cy); cy = fmaf(w1, ry * vf0[i].y, cy);
        }
        nt_store2(make_float2((1.0f - ux) * vf0[o].x + ux * tanh_fast(cx),
                              (1.0f - uy) * vf0[o].y + uy * tanh_fast(cy)),
                  node0 + base + o * HW);
    }

    __syncthreads();
    if (tid < 40) atomicAdd(&stats[tid], sPart[tid] + sPart[40 + tid]);
}

// ---------------- K2: recompute att+y1, BN1+ReLU, y2, BN2 stats (atomic) ----------------
__global__ __launch_bounds__(TPB, 1) void kernC(
    const float* __restrict__ f1, const float* __restrict__ h1, const float* __restrict__ h2,
    const float* __restrict__ W_att, const float* __restrict__ b_att,
    const float* __restrict__ W_r1, const float* __restrict__ g_r1, const float* __restrict__ be_r1,
    const float* __restrict__ W_r2,
    float* __restrict__ stats, float* __restrict__ y2out)
{
    __shared__ float sPart[2 * 20];
    const int tid = threadIdx.x, wave = tid >> 6, lane = tid & 63;
    const int g = blockIdx.x * TPB + tid;
    const int b = g >> 13, sp = (g & 8191) << 1;
    const int base = b * (10 * HW) + sp;

    float2 vf1[10], vh1[10], vh2[10];
#pragma unroll
    for (int c = 0; c < 10; c++) {
        vh1[c] = ld2(h1 + base + c * HW);
        vh2[c] = ld2(h2 + base + c * HW);
        vf1[c] = ld2(f1 + base + c * HW);
    }

    // recompute att (cheaper than a global round-trip)
    float zx = b_att[0], zy = zx;
#pragma unroll
    for (int c = 0; c < 10; c++) {
        zx += W_att[c] * vh1[c].x + W_att[10 + c] * vh2[c].x;
        zy += W_att[c] * vh1[c].y + W_att[10 + c] * vh2[c].y;
    }
    const float ax_ = sigf(zx), ay_ = sigf(zy);

    float2 x[20];
#pragma unroll
    for (int c = 0; c < 10; c++) {
        x[c] = vf1[c];
        x[10 + c] = make_float2((vh1[c].x + vh2[c].x) * ax_,
                                (vh1[c].y + vh2[c].y) * ay_);
    }

    // y1 -> BN1 (coeffs inline from scalar-loaded stats) -> ReLU
    float2 x2[20];
#pragma unroll
    for (int o = 0; o < 20; o++) {
        float sx = 0.0f, sy = 0.0f;
#pragma unroll
        for (int i = 0; i < 20; i++) {
            const float w = W_r1[o * 20 + i];
            sx = fmaf(w, x[i].x, sx);
            sy = fmaf(w, x[i].y, sy);
        }
        const float mean = stats[o] * (1.0f / BN_N);
        const float var  = stats[20 + o] * (1.0f / BN_N) - mean * mean;
        const float a = g_r1[o] * rsqrtf(var + EPS_BN);
        const float bb = be_r1[o] - mean * a;
        x2[o] = make_float2(fmaxf(fmaf(a, sx, bb), 0.0f),
                            fmaxf(fmaf(a, sy, bb), 0.0f));
    }

    // y2 = W_r2 @ x2 ; store + BN2 stats
#pragma unroll
    for (int o = 0; o < 10; o++) {
        float sx = 0.0f, sy = 0.0f;
#pragma unroll
        for (int i = 0; i < 20; i++) {
            const float w = W_r2[o * 20 + i];
            sx = fmaf(w, x2[i].x, sx);
            sy = fmaf(w, x2[i].y, sy);
        }
        *(float2*)(y2out + base + o * HW) = make_float2(sx, sy);
        float rs = wred(sx + sy);
        float rq = wred(sx * sx + sy * sy);
        if (lane == 0) { sPart[wave * 20 + o] = rs; sPart[wave * 20 + 10 + o] = rq; }
    }
    __syncthreads();
    if (tid < 20) atomicAdd(&stats[40 + tid], sPart[tid] + sPart[20 + tid]);
}

// ---------------- K3: BN2, comp_full, node1 (GRU1) ----------------
__global__ __launch_bounds__(TPB, 1) void kernE(
    const float* __restrict__ f1, const float* __restrict__ y2in,
    const float* __restrict__ stats,
    const float* __restrict__ g_r2, const float* __restrict__ be_r2,
    const float* __restrict__ Wg1, const float* __restrict__ bg1, const float* __restrict__ Wc1,
    float* __restrict__ node1)
{
    const int tid = threadIdx.x;
    const int g = blockIdx.x * TPB + tid;
    const int b = g >> 13, sp = (g & 8191) << 1;
    const int base = b * (10 * HW) + sp;

    float2 vf1[10], vy2[10];
#pragma unroll
    for (int c = 0; c < 10; c++) {
        vf1[c] = ld2(f1 + base + c * HW);
        vy2[c] = ld2(y2in + base + c * HW);
    }

    float2 comp[10];
#pragma unroll
    for (int c = 0; c < 10; c++) {
        const float mean = stats[40 + c] * (1.0f / BN_N);
        const float var  = stats[50 + c] * (1.0f / BN_N) - mean * mean;
        const float a = g_r2[c] * rsqrtf(var + EPS_BN);
        const float bb = be_r2[c] - mean * a;
        comp[c] = make_float2(fmaxf(fmaf(a, vy2[c].x, bb), 0.0f),
                              fmaxf(fmaf(a, vy2[c].y, bb), 0.0f));
    }

    float g0x = bg1[0], g1x = bg1[1], g0y = bg1[0], g1y = bg1[1];
#pragma unroll
    for (int i = 0; i < 10; i++) {
        g0x += Wg1[i] * comp[i].x + Wg1[10 + i] * vf1[i].x;
        g0y += Wg1[i] * comp[i].y + Wg1[10 + i] * vf1[i].y;
        g1x += Wg1[20 + i] * comp[i].x + Wg1[30 + i] * vf1[i].x;
        g1y += Wg1[20 + i] * comp[i].y + Wg1[30 + i] * vf1[i].y;
    }
    const float rx = sigf(g0x), ux = sigf(g1x);
    const float ry = sigf(g0y), uy = sigf(g1y);
#pragma unroll
    for (int o = 0; o < 10; o++) {
        float cx = 0.0f, cy = 0.0f;
#pragma unroll
        for (int i = 0; i < 10; i++) {
            const float w0 = Wc1[o * 20 + i], w1 = Wc1[o * 20 + 10 + i];
            cx = fmaf(w0, comp[i].x, cx); cx = fmaf(w1, rx * vf1[i].x, cx);
            cy = fmaf(w0, comp[i].y, cy); cy = fmaf(w1, ry * vf1[i].y, cy);
        }
        nt_store2(make_float2((1.0f - ux) * vf1[o].x + ux * tanh_fast(cx),
                              (1.0f - uy) * vf1[o].y + uy * tanh_fast(cy)),
                  node1 + base + o * HW);
    }
}

extern "C" void kernel_launch(void* const* d_in, const int* in_sizes, int n_in,
                              void* d_out, int out_size, void* d_ws, size_t ws_size,
                              hipStream_t stream) {
    const float* f0    = (const float*)d_in[0];
    const float* f1    = (const float*)d_in[1];
    const float* h0    = (const float*)d_in[2];
    const float* h1    = (const float*)d_in[3];
    const float* h2    = (const float*)d_in[4];
    const float* W_att = (const float*)d_in[5];
    const float* b_att = (const float*)d_in[6];
    const float* W_r1  = (const float*)d_in[7];
    const float* g_r1  = (const float*)d_in[8];
    const float* be_r1 = (const float*)d_in[9];
    const float* W_r2  = (const float*)d_in[10];
    const float* g_r2  = (const float*)d_in[11];
    const float* be_r2 = (const float*)d_in[12];
    const float* Wg0   = (const float*)d_in[13];
    const float* bg0   = (const float*)d_in[14];
    const float* Wc0   = (const float*)d_in[15];
    const float* Wg1   = (const float*)d_in[16];
    const float* bg1   = (const float*)d_in[17];
    const float* Wc1   = (const float*)d_in[18];

    float* out   = (float*)d_out;
    float* node0 = out;
    float* node1 = out + NPLANE;
    float* attO  = out + 2 * NPLANE;

    float* stats = (float*)d_ws;            // 60 floats: [0:20]s1 [20:40]q1 [40:50]s2 [50:60]q2
    float* y2    = stats + 64;              // 10*NPIX floats

    hipMemsetAsync(stats, 0, 64 * sizeof(float), stream);

    dim3 grid(NBLK), blk(TPB);
    kernA<<<grid, blk, 0, stream>>>(f0, f1, h0, h1, h2, W_att, b_att, W_r1,
                                    Wg0, bg0, Wc0, node0, attO, stats);
    kernC<<<grid, blk, 0, stream>>>(f1, h1, h2, W_att, b_att, W_r1, g_r1, be_r1,
                                    W_r2, stats, y2);
    kernE<<<grid, blk, 0, stream>>>(f1, y2, stats, g_r2, be_r2, Wg1, bg1, Wc1,
                                    node1);
}